// Round 10
// baseline (56.401 us; speedup 1.0000x reference)
//
#include <hip/hip_runtime.h>

#define N    1024
#define HALF 512
#define HD   64
#define MD   32
#define BLK  256        // k_p0 / fin block
#define BLKP 512        // pair-kernel block: 8 waves
#define WROW (2 * HD + 1)   // 129, w_msg row stride
#define PS   80         // part stride (floats): [0..5]=vA,vB [6..8]=Sx [16..47]=msA [48..79]=msB

// ---------------------------------------------------------------------------
// P0: h0 = feat + posenc; A1/B1 projections. One block per 4 rows.
// ---------------------------------------------------------------------------
__global__ __launch_bounds__(BLK) void k_p0(const float* __restrict__ feat,
                                            const float* __restrict__ wmsg,
                                            const float* __restrict__ bmsg,
                                            float* __restrict__ h0,
                                            float* __restrict__ A,
                                            float* __restrict__ Bb)
{
    __shared__ float scr[4160 + 4 * HD];
    const int tid = threadIdx.x;
    const int n0  = blockIdx.x * 4;

    for (int u = tid; u < MD * WROW; u += BLK) scr[u] = wmsg[u];   // 4128 floats
    float* hrow = scr + 4160;
    {
        const int n = n0 + (tid >> 6), d = tid & 63;
        const float div = expf((float)(d & ~1) * (-9.210340371976184f / 64.0f));
        const float ang = (float)n * div;
        const float pe  = (d & 1) ? cosf(ang) : sinf(ang);
        const float hv  = feat[n * HD + d] + pe;
        h0[n * HD + d] = hv;
        hrow[tid] = hv;
    }
    __syncthreads();
    if (tid < 4 * MD) {
        const int nl = tid >> 5, m = tid & 31;
        const float* wa = scr + m * WROW;          // stride 129: conflict-free
        const float* hr = hrow + nl * HD;
        float sa = 0.f, sb = bmsg[m];
#pragma unroll
        for (int c = 0; c < HD; c++) {
            const float hv = hr[c];
            sa = fmaf(hv, wa[c], sa);
            sb = fmaf(hv, wa[HD + c], sb);
        }
        const int n = n0 + nl;
        A[n * MD + m]  = sa;
        Bb[n * MD + m] = sb;
    }
}

// ---------------------------------------------------------------------------
// Pair-partial kernel: grid 1024. bb = bid&511 -> rows (bb, bb+512);
// half = bid>>9 -> j in [half*512, half*512+512). Block 512 thr = 8 waves,
// wave w owns 64 j's (8 iters). Lane map: kq = lane>>3 (4 k's via float4),
// jslot = lane&7.  Writes partial v/Sx/msum to part[bid].
// ---------------------------------------------------------------------------
template<int WRITE_MS>
__global__ __launch_bounds__(BLKP) void k_pairp(
    const float* __restrict__ xsrc, const float* __restrict__ Aap,
    const float* __restrict__ Bbp, const float* __restrict__ wmsg,
    const float* __restrict__ wpos, float* __restrict__ part)
{
    const int tid   = threadIdx.x;
    const int wid   = tid >> 6;         // 0..7
    const int lane  = tid & 63;
    const int jslot = lane & 7;
    const int kq    = lane >> 3;

    __shared__ float4 rdA[HALF];        // 8 KB
    __shared__ float4 rdB[HALF];        // 8 KB
    __shared__ float  sxacc[8][3];
    __shared__ float  wacc[8][6];
    __shared__ float  msAl[8][MD];
    __shared__ float  msBl[8][MD];

    const int bb   = blockIdx.x & (HALF - 1);
    const int half = blockIdx.x >> 9;
    const int iA = bb, iB = bb + HALF;
    const int j0 = half * HALF;

    const float xiA0 = xsrc[iA * 3 + 0], xiA1 = xsrc[iA * 3 + 1], xiA2 = xsrc[iA * 3 + 2];
    const float xiB0 = xsrc[iB * 3 + 0], xiB1 = xsrc[iB * 3 + 1], xiB2 = xsrc[iB * 3 + 2];

    // ---- stage r/d2 tables for this j-half; Sx partial ----
    {
        const int j = j0 + tid;
        const float xj0 = xsrc[j * 3 + 0];
        const float xj1 = xsrc[j * 3 + 1];
        const float xj2 = xsrc[j * 3 + 2];
        float sx0 = xj0, sx1 = xj1, sx2 = xj2;
        float r0 = xj0 - xiA0, r1 = xj1 - xiA1, r2 = xj2 - xiA2;
        rdA[tid] = make_float4(r0, r1, r2, fmaf(r0, r0, fmaf(r1, r1, r2 * r2)));
        r0 = xj0 - xiB0; r1 = xj1 - xiB1; r2 = xj2 - xiB2;
        rdB[tid] = make_float4(r0, r1, r2, fmaf(r0, r0, fmaf(r1, r1, r2 * r2)));
#pragma unroll
        for (int off = 32; off > 0; off >>= 1) {
            sx0 += __shfl_xor(sx0, off);
            sx1 += __shfl_xor(sx1, off);
            sx2 += __shfl_xor(sx2, off);
        }
        if (lane == 0) { sxacc[wid][0] = sx0; sxacc[wid][1] = sx1; sxacc[wid][2] = sx2; }
    }

    // ---- per-lane weights for the 4 owned k's ----
    const float4 biA4 = *(const float4*)(Bbp + iA * MD + kq * 4);
    const float4 biB4 = *(const float4*)(Bbp + iB * MD + kq * 4);
    const float4 wpx4 = *(const float4*)(wpos + kq * 4);
    const float4 wpy4 = *(const float4*)(wpos + MD + kq * 4);
    const float4 wpz4 = *(const float4*)(wpos + 2 * MD + kq * 4);
    float wd4[4];
#pragma unroll
    for (int kk = 0; kk < 4; kk++) wd4[kk] = wmsg[(kq * 4 + kk) * WROW + 2 * HD];
    const float biA[4] = {biA4.x, biA4.y, biA4.z, biA4.w};
    const float biB[4] = {biB4.x, biB4.y, biB4.z, biB4.w};
    const float wpx[4] = {wpx4.x, wpx4.y, wpx4.z, wpx4.w};
    const float wpy[4] = {wpy4.x, wpy4.y, wpy4.z, wpy4.w};
    const float wpz[4] = {wpz4.x, wpz4.y, wpz4.z, wpz4.w};

    float PAx[4] = {0,0,0,0}, PAy[4] = {0,0,0,0}, PAz[4] = {0,0,0,0};
    float PBx[4] = {0,0,0,0}, PBy[4] = {0,0,0,0}, PBz[4] = {0,0,0,0};
    float msA[4] = {0,0,0,0}, msB[4] = {0,0,0,0};

    __syncthreads();                       // rd tables + sxacc ready

    const int jbl = wid * 64;              // 64 j per wave (local index)
#pragma unroll 8
    for (int it = 0; it < 8; it++) {
        const int jl = jbl + it * 8 + jslot;
        const float4 a4 = *(const float4*)(Aap + (j0 + jl) * MD + kq * 4);
        const float4 fA = rdA[jl];         // 8-way broadcast per address
        const float4 fB = rdB[jl];
        const float av[4] = {a4.x, a4.y, a4.z, a4.w};
#pragma unroll
        for (int kk = 0; kk < 4; kk++) {
            const float mA = fmaxf(fmaf(fA.w, wd4[kk], av[kk] + biA[kk]), 0.f);
            const float mB = fmaxf(fmaf(fB.w, wd4[kk], av[kk] + biB[kk]), 0.f);
            if (WRITE_MS) { msA[kk] += mA; msB[kk] += mB; }
            PAx[kk] = fmaf(mA, fA.x, PAx[kk]);
            PAy[kk] = fmaf(mA, fA.y, PAy[kk]);
            PAz[kk] = fmaf(mA, fA.z, PAz[kk]);
            PBx[kk] = fmaf(mB, fB.x, PBx[kk]);
            PBy[kk] = fmaf(mB, fB.y, PBy[kk]);
            PBz[kk] = fmaf(mB, fB.z, PBz[kk]);
        }
    }

    // ---- fold wp per lane, reduce across 64 lanes ----
    float vA0 = 0.f, vA1 = 0.f, vA2 = 0.f, vB0 = 0.f, vB1 = 0.f, vB2 = 0.f;
#pragma unroll
    for (int kk = 0; kk < 4; kk++) {
        vA0 = fmaf(PAx[kk], wpx[kk], vA0);
        vA1 = fmaf(PAy[kk], wpy[kk], vA1);
        vA2 = fmaf(PAz[kk], wpz[kk], vA2);
        vB0 = fmaf(PBx[kk], wpx[kk], vB0);
        vB1 = fmaf(PBy[kk], wpy[kk], vB1);
        vB2 = fmaf(PBz[kk], wpz[kk], vB2);
    }
#pragma unroll
    for (int off = 32; off > 0; off >>= 1) {
        vA0 += __shfl_xor(vA0, off); vA1 += __shfl_xor(vA1, off); vA2 += __shfl_xor(vA2, off);
        vB0 += __shfl_xor(vB0, off); vB1 += __shfl_xor(vB1, off); vB2 += __shfl_xor(vB2, off);
    }
    if (WRITE_MS) {
#pragma unroll
        for (int off = 1; off <= 4; off <<= 1) {
#pragma unroll
            for (int kk = 0; kk < 4; kk++) {
                msA[kk] += __shfl_xor(msA[kk], off);
                msB[kk] += __shfl_xor(msB[kk], off);
            }
        }
    }
    if (lane == 0) {
        wacc[wid][0] = vA0; wacc[wid][1] = vA1; wacc[wid][2] = vA2;
        wacc[wid][3] = vB0; wacc[wid][4] = vB1; wacc[wid][5] = vB2;
    }
    if (WRITE_MS && jslot == 0) {
#pragma unroll
        for (int kk = 0; kk < 4; kk++) {
            msAl[wid][kq * 4 + kk] = msA[kk];
            msBl[wid][kq * 4 + kk] = msB[kk];
        }
    }
    __syncthreads();

    float* po = part + blockIdx.x * PS;
    if (tid == 0) {
#pragma unroll
        for (int c = 0; c < 6; c++) {
            float s = 0.f;
#pragma unroll
            for (int w = 0; w < 8; w++) s += wacc[w][c];
            po[c] = s;
        }
#pragma unroll
        for (int c = 0; c < 3; c++) {
            float s = 0.f;
#pragma unroll
            for (int w = 0; w < 8; w++) s += sxacc[w][c];
            po[6 + c] = s;
        }
    }
    if (WRITE_MS && tid < 2 * MD) {
        const int row = tid >> 5, k = tid & 31;
        const float (*ml)[MD] = row ? msBl : msAl;
        float s = 0.f;
#pragma unroll
        for (int w = 0; w < 8; w++) s += ml[w][k];
        po[16 + row * 32 + k] = s;
    }
}

// ---------------------------------------------------------------------------
// fin1: per row-pair bb: combine partials -> x1 rows, msum (diag-corrected),
// h1 = relu([h0,msum]@wf.T+bf), A2/B2 rows.
// ---------------------------------------------------------------------------
__global__ __launch_bounds__(BLK) void k_fin1(
    const float* __restrict__ xsrc, const float* __restrict__ part,
    const float* __restrict__ Aap, const float* __restrict__ Bbp,
    const float* __restrict__ bpos, const float* __restrict__ h0,
    const float* __restrict__ wf, const float* __restrict__ bf,
    const float* __restrict__ wmsg2, const float* __restrict__ bmsg2,
    float* __restrict__ x1, float* __restrict__ A2, float* __restrict__ B2)
{
    __shared__ float scr[6208];
    __shared__ float msF[2][MD], h0r[2][HD], h1r[2][HD];
    const int tid = threadIdx.x;
    const int bb  = blockIdx.x;
    const int iA = bb, iB = bb + HALF;
    const float* p0 = part + bb * PS;
    const float* p1 = part + (bb + HALF) * PS;

    if (tid < 2 * MD) {                    // msum rows with diagonal correction
        const int row = tid >> 5, k = tid & 31;
        const int i = row ? iB : iA;
        float s = p0[16 + row * 32 + k] + p1[16 + row * 32 + k];
        s -= fmaxf(Aap[i * MD + k] + Bbp[i * MD + k], 0.f);   // d2=0 at j==i
        msF[row][k] = s;
    }
    for (int u = tid; u < HD * (HD + MD); u += BLK) {          // stage wf
        const int o = u / (HD + MD), c = u - o * (HD + MD);
        scr[o * 97 + c] = wf[u];
    }
    if (tid < 2 * HD) {
        const int row = tid >> 6, d = tid & 63;
        h0r[row][d] = h0[(row ? iB : iA) * HD + d];
    }
    if (tid == 0) {                        // x1 rows
        const float bp[3] = {bpos[0], bpos[1], bpos[2]};
        const float inv = 1.0f / 1023.0f;
#pragma unroll
        for (int c = 0; c < 3; c++) {
            const float Sx = p0[6 + c] + p1[6 + c];
            const float xa = xsrc[iA * 3 + c];
            const float xb = xsrc[iB * 3 + c];
            x1[iA * 3 + c] = xa + (p0[c] + p1[c] + bp[c] * (Sx - (float)N * xa)) * inv;
            x1[iB * 3 + c] = xb + (p0[3 + c] + p1[3 + c] + bp[c] * (Sx - (float)N * xb)) * inv;
        }
    }
    __syncthreads();
    if (tid < 2 * HD) {                    // h1 rows
        const int row = tid >> 6, o = tid & 63;
        const float* w = scr + o * 97;
        float s = bf[o];
#pragma unroll
        for (int c = 0; c < HD; c++) s = fmaf(h0r[row][c], w[c], s);
#pragma unroll
        for (int k = 0; k < MD; k++) s = fmaf(msF[row][k], w[HD + k], s);
        h1r[row][o] = fmaxf(s, 0.f);
    }
    __syncthreads();
    for (int u = tid; u < MD * WROW; u += BLK) scr[u] = wmsg2[u];
    __syncthreads();
    if (tid < 2 * MD) {                    // A2/B2 rows
        const int row = tid >> 5, m = tid & 31;
        const float* wa = scr + m * WROW;
        const float* hr = h1r[row];
        float sa = 0.f, sb = bmsg2[m];
#pragma unroll
        for (int c = 0; c < HD; c++) {
            const float hv = hr[c];
            sa = fmaf(hv, wa[c], sa);
            sb = fmaf(hv, wa[HD + c], sb);
        }
        const int i = row ? iB : iA;
        A2[i * MD + m] = sa;
        B2[i * MD + m] = sb;
    }
}

// ---------------------------------------------------------------------------
// fin2: combine partials -> x_out. One thread per row, grid N/256.
// ---------------------------------------------------------------------------
__global__ __launch_bounds__(BLK) void k_fin2(
    const float* __restrict__ xsrc, const float* __restrict__ part,
    const float* __restrict__ bpos, float* __restrict__ out)
{
    const int i = blockIdx.x * BLK + threadIdx.x;
    const int bb = i & (HALF - 1), row = i >> 9;
    const float* p0 = part + bb * PS;
    const float* p1 = part + (bb + HALF) * PS;
    const float inv = 1.0f / 1023.0f;
#pragma unroll
    for (int c = 0; c < 3; c++) {
        const float Sx = p0[6 + c] + p1[6 + c];
        const float v  = p0[row * 3 + c] + p1[row * 3 + c];
        const float xi = xsrc[i * 3 + c];
        out[i * 3 + c] = xi + (v + bpos[c] * (Sx - (float)N * xi)) * inv;
    }
}

// ---------------------------------------------------------------------------
extern "C" void kernel_launch(void* const* d_in, const int* in_sizes, int n_in,
                              void* d_out, int out_size, void* d_ws, size_t ws_size,
                              hipStream_t stream)
{
    const float* pos     = (const float*)d_in[0];
    const float* feat    = (const float*)d_in[1];
    const float* w_msg1  = (const float*)d_in[3];
    const float* b_msg1  = (const float*)d_in[4];
    const float* w_pos1  = (const float*)d_in[5];
    const float* b_pos1  = (const float*)d_in[6];
    const float* w_feat1 = (const float*)d_in[7];
    const float* b_feat1 = (const float*)d_in[8];
    const float* w_msg2  = (const float*)d_in[9];
    const float* b_msg2  = (const float*)d_in[10];
    const float* w_pos2  = (const float*)d_in[11];
    const float* b_pos2  = (const float*)d_in[12];

    float* ws   = (float*)d_ws;
    float* h0   = ws;                  // N*HD
    float* A1   = h0  + N * HD;        // N*MD
    float* B1   = A1  + N * MD;
    float* x1   = B1  + N * MD;        // N*4 (padded)
    float* A2   = x1  + N * 4;
    float* B2   = A2  + N * MD;
    float* part = B2  + N * MD;        // 1024*PS

    k_p0<<<N / 4, BLK, 0, stream>>>(feat, w_msg1, b_msg1, h0, A1, B1);
    k_pairp<1><<<2 * HALF, BLKP, 0, stream>>>(pos, A1, B1, w_msg1, w_pos1, part);
    k_fin1<<<HALF, BLK, 0, stream>>>(pos, part, A1, B1, b_pos1, h0,
                                     w_feat1, b_feat1, w_msg2, b_msg2, x1, A2, B2);
    k_pairp<0><<<2 * HALF, BLKP, 0, stream>>>(x1, A2, B2, w_msg2, w_pos2, part);
    k_fin2<<<N / BLK, BLK, 0, stream>>>(x1, part, b_pos2, (float*)d_out);
}